// Round 1
// baseline (641.082 us; speedup 1.0000x reference)
//
#include <hip/hip_runtime.h>
#include <math.h>

#define NN 50000
#define EE 800000
#define ET (EE + NN)
#define FIN 256
#define CCOUT 128
#define HH 2
#define HC 256
#define NEG 0.2f

#define NB_EDGE ((ET + 255) / 256)
#define NB_SCAN ((NN + 255) / 256)

// ---------------- detect int32 vs int64 edge_index layout ----------------
__global__ void detect_kernel(const int* __restrict__ ei32, int* __restrict__ flag)
{
    if (threadIdx.x == 0 && blockIdx.x == 0) {
        int is64 = 1;
        for (int k = 0; k < 32; k++) {
            if (ei32[2 * k + 1] != 0) { is64 = 0; break; }
        }
        *flag = is64;
    }
}

__device__ __forceinline__ int load_idx(const int* ei32, int is64, int pos)
{
    return is64 ? ei32[2 * pos] : ei32[pos];
}

// ---------------- GEMM: C = A[M,K] @ B[Nc,K]^T (+ bias) ----------------
template <bool ADD_BIAS>
__global__ __launch_bounds__(256) void gemm_nt(const float* __restrict__ A,
                                               const float* __restrict__ B,
                                               const float* __restrict__ bias,
                                               float* __restrict__ C,
                                               int M, int Nc, int K)
{
    const int BM = 64, BN = 64, BK = 16;
    __shared__ float As[BK][BM + 4];
    __shared__ float Bs[BK][BN + 4];
    int tid = threadIdx.x;
    int bm0 = blockIdx.x * BM;
    int bn0 = blockIdx.y * BN;
    int tx = tid & 15, ty = tid >> 4;
    int lr = tid >> 2;        // 0..63
    int lc = (tid & 3) * 4;   // 0,4,8,12
    float acc[4][4] = {};

    for (int kk = 0; kk < K; kk += BK) {
        int ga = bm0 + lr;
        float4 av;
        if (ga < M) av = *(const float4*)(A + (size_t)ga * K + kk + lc);
        else av = make_float4(0.f, 0.f, 0.f, 0.f);
        As[lc + 0][lr] = av.x; As[lc + 1][lr] = av.y;
        As[lc + 2][lr] = av.z; As[lc + 3][lr] = av.w;
        float4 bv = *(const float4*)(B + (size_t)(bn0 + lr) * K + kk + lc);
        Bs[lc + 0][lr] = bv.x; Bs[lc + 1][lr] = bv.y;
        Bs[lc + 2][lr] = bv.z; Bs[lc + 3][lr] = bv.w;
        __syncthreads();
#pragma unroll
        for (int k = 0; k < BK; k++) {
            float4 a = *(const float4*)&As[k][ty * 4];
            float4 b = *(const float4*)&Bs[k][tx * 4];
            acc[0][0] += a.x * b.x; acc[0][1] += a.x * b.y; acc[0][2] += a.x * b.z; acc[0][3] += a.x * b.w;
            acc[1][0] += a.y * b.x; acc[1][1] += a.y * b.y; acc[1][2] += a.y * b.z; acc[1][3] += a.y * b.w;
            acc[2][0] += a.z * b.x; acc[2][1] += a.z * b.y; acc[2][2] += a.z * b.z; acc[2][3] += a.z * b.w;
            acc[3][0] += a.w * b.x; acc[3][1] += a.w * b.y; acc[3][2] += a.w * b.z; acc[3][3] += a.w * b.w;
        }
        __syncthreads();
    }

#pragma unroll
    for (int i = 0; i < 4; i++) {
        int row = bm0 + ty * 4 + i;
        if (row < M) {
            float4 v = make_float4(acc[i][0], acc[i][1], acc[i][2], acc[i][3]);
            if (ADD_BIAS) {
                int col = bn0 + tx * 4;
                v.x += bias[col + 0]; v.y += bias[col + 1];
                v.z += bias[col + 2]; v.w += bias[col + 3];
            }
            *(float4*)(C + (size_t)row * Nc + bn0 + tx * 4) = v;
        }
    }
}

// ---------------- per-node attention logits ----------------
__global__ __launch_bounds__(256) void att_kernel(const float* __restrict__ h,
                                                  const float* __restrict__ att_s,
                                                  const float* __restrict__ att_d,
                                                  float* __restrict__ a_s,
                                                  float* __restrict__ a_d)
{
    int n = blockIdx.x;
    int t = threadIdx.x;
    float hv = h[(size_t)n * HC + t];
    float vs = hv * att_s[t];
    float vd = hv * att_d[t];
#pragma unroll
    for (int off = 32; off > 0; off >>= 1) {
        vs += __shfl_down(vs, off);
        vd += __shfl_down(vd, off);
    }
    __shared__ float ss[4], sd[4];
    int w = t >> 6;
    if ((t & 63) == 0) { ss[w] = vs; sd[w] = vd; }
    __syncthreads();
    if (t == 0) {
        a_s[n * 2 + 0] = ss[0] + ss[1];
        a_s[n * 2 + 1] = ss[2] + ss[3];
        a_d[n * 2 + 0] = sd[0] + sd[1];
        a_d[n * 2 + 1] = sd[2] + sd[3];
    }
}

// ---------------- degree count ----------------
__global__ void count_kernel(const int* __restrict__ ei32, const int* __restrict__ flag,
                             int* __restrict__ deg)
{
    int e = blockIdx.x * blockDim.x + threadIdx.x;
    if (e >= ET) return;
    int is64 = *flag;
    int d = (e < EE) ? load_idx(ei32, is64, EE + e) : (e - EE);
    atomicAdd(&deg[d], 1);
}

// ---------------- 3-kernel exclusive scan over deg[NN] ----------------
__global__ __launch_bounds__(256) void scan1(const int* __restrict__ deg,
                                             int* __restrict__ tmp, int* __restrict__ bsum)
{
    __shared__ int s[256];
    int i = blockIdx.x * 256 + threadIdx.x;
    int v = (i < NN) ? deg[i] : 0;
    s[threadIdx.x] = v;
    __syncthreads();
    for (int off = 1; off < 256; off <<= 1) {
        int add = (threadIdx.x >= off) ? s[threadIdx.x - off] : 0;
        __syncthreads();
        s[threadIdx.x] += add;
        __syncthreads();
    }
    if (i < NN) tmp[i] = s[threadIdx.x];
    if (threadIdx.x == 255) bsum[blockIdx.x] = s[255];
}

__global__ __launch_bounds__(256) void scan2(int* __restrict__ bsum)
{
    __shared__ int s[256];
    int t = threadIdx.x;
    int v = (t < NB_SCAN) ? bsum[t] : 0;
    s[t] = v;
    __syncthreads();
    for (int off = 1; off < 256; off <<= 1) {
        int add = (t >= off) ? s[t - off] : 0;
        __syncthreads();
        s[t] += add;
        __syncthreads();
    }
    if (t < NB_SCAN) bsum[t] = s[t] - v;  // exclusive block offsets
}

__global__ __launch_bounds__(256) void scan3(const int* __restrict__ deg,
                                             const int* __restrict__ tmp,
                                             const int* __restrict__ bsum,
                                             int* __restrict__ rowstart)
{
    int i = blockIdx.x * 256 + threadIdx.x;
    if (i < NN) rowstart[i] = tmp[i] - deg[i] + bsum[blockIdx.x];
    if (i == 0) rowstart[NN] = ET;
}

// ---------------- scatter edges into CSR + denom ----------------
__global__ void scatter_kernel(const int* __restrict__ ei32, const int* __restrict__ flag,
                               const float* __restrict__ a_s, const float* __restrict__ a_d,
                               const int* __restrict__ rowstart, int* __restrict__ cursor,
                               int* __restrict__ csr_src, float* __restrict__ csr_p,
                               float* __restrict__ denom)
{
    int e = blockIdx.x * blockDim.x + threadIdx.x;
    if (e >= ET) return;
    int is64 = *flag;
    int s, d;
    if (e < EE) { s = load_idx(ei32, is64, e); d = load_idx(ei32, is64, EE + e); }
    else { s = d = e - EE; }
    float e0 = a_s[s * 2 + 0] + a_d[d * 2 + 0];
    float e1 = a_s[s * 2 + 1] + a_d[d * 2 + 1];
    e0 = e0 > 0.f ? e0 : NEG * e0;
    e1 = e1 > 0.f ? e1 : NEG * e1;
    float p0 = expf(e0);
    float p1 = expf(e1);
    int j = rowstart[d] + atomicAdd(&cursor[d], 1);
    csr_src[j] = s;
    csr_p[2 * j + 0] = p0;
    csr_p[2 * j + 1] = p1;
    atomicAdd(&denom[d * 2 + 0], p0);
    atomicAdd(&denom[d * 2 + 1], p1);
}

// ---------------- gather-aggregate per destination node + bias + elu ----------------
__global__ __launch_bounds__(256) void agg_kernel(const float* __restrict__ h,
                                                  const int* __restrict__ rowstart,
                                                  const int* __restrict__ csr_src,
                                                  const float* __restrict__ csr_p,
                                                  const float* __restrict__ denom,
                                                  const float* __restrict__ bias,
                                                  float* __restrict__ agg)
{
    int d = blockIdx.x;
    int t = threadIdx.x;
    int head = t >> 7;
    int j0 = rowstart[d], j1 = rowstart[d + 1];
    float acc = 0.f;
    for (int j = j0; j < j1; j++) {
        int s = csr_src[j];
        float p = csr_p[2 * j + head];
        acc += p * h[(size_t)s * HC + t];
    }
    float den = denom[d * 2 + head];
    float v = acc / fmaxf(den, 1e-16f) + bias[t];
    v = v > 0.f ? v : expm1f(v);   // ELU(alpha=1)
    agg[(size_t)d * HC + t] = v;
}

// ---------------- launch ----------------
extern "C" void kernel_launch(void* const* d_in, const int* in_sizes, int n_in,
                              void* d_out, int out_size, void* d_ws, size_t ws_size,
                              hipStream_t stream)
{
    const float* x       = (const float*)d_in[0];
    const int*   ei32    = (const int*)d_in[1];
    const float* W       = (const float*)d_in[2];
    const float* att_src = (const float*)d_in[3];
    const float* att_dst = (const float*)d_in[4];
    const float* bias    = (const float*)d_in[5];
    const float* lin_w   = (const float*)d_in[6];
    const float* lin_b   = (const float*)d_in[7];
    float* out = (float*)d_out;

    char* ws = (char*)d_ws;
    size_t off = 0;
    auto alloc = [&](size_t bytes) -> void* {
        void* p = ws + off;
        off += (bytes + 255) & ~(size_t)255;
        return p;
    };

    // zero-init region first (deg, cursor, denom)
    int*   deg    = (int*)alloc((size_t)NN * 4);
    int*   cursor = (int*)alloc((size_t)NN * 4);
    float* denom  = (float*)alloc((size_t)NN * 2 * 4);
    size_t zero_bytes = off;

    int*   flag     = (int*)alloc(256);
    int*   tmp      = (int*)alloc((size_t)NN * 4);
    int*   bsum     = (int*)alloc(1024);
    int*   rowstart = (int*)alloc((size_t)(NN + 1) * 4);
    float* a_s      = (float*)alloc((size_t)NN * 2 * 4);
    float* a_d      = (float*)alloc((size_t)NN * 2 * 4);
    int*   csr_src  = (int*)alloc((size_t)ET * 4);
    float* csr_p    = (float*)alloc((size_t)ET * 2 * 4);
    float* h        = (float*)alloc((size_t)NN * HC * 4);
    float* agg      = (float*)alloc((size_t)NN * HC * 4);

    hipMemsetAsync(d_ws, 0, zero_bytes, stream);

    detect_kernel<<<1, 64, 0, stream>>>(ei32, flag);

    dim3 g1((NN + 63) / 64, FIN / 64);
    gemm_nt<false><<<g1, 256, 0, stream>>>(x, W, nullptr, h, NN, HC, FIN);

    att_kernel<<<NN, 256, 0, stream>>>(h, att_src, att_dst, a_s, a_d);

    count_kernel<<<NB_EDGE, 256, 0, stream>>>(ei32, flag, deg);

    scan1<<<NB_SCAN, 256, 0, stream>>>(deg, tmp, bsum);
    scan2<<<1, 256, 0, stream>>>(bsum);
    scan3<<<NB_SCAN, 256, 0, stream>>>(deg, tmp, bsum, rowstart);

    scatter_kernel<<<NB_EDGE, 256, 0, stream>>>(ei32, flag, a_s, a_d, rowstart,
                                                cursor, csr_src, csr_p, denom);

    agg_kernel<<<NN, 256, 0, stream>>>(h, rowstart, csr_src, csr_p, denom, bias, agg);

    dim3 g2((NN + 63) / 64, CCOUT / 64);
    gemm_nt<true><<<g2, 256, 0, stream>>>(agg, lin_w, lin_b, out, NN, CCOUT, HC);
}

// Round 2
// 428.918 us; speedup vs baseline: 1.4946x; 1.4946x over previous
//
#include <hip/hip_runtime.h>
#include <math.h>

#define NN 50000
#define EE 800000
#define ET (EE + NN)
#define FIN 256
#define CCOUT 128
#define HH 2
#define HC 256
#define NEG 0.2f

#define NB_EDGE ((ET + 255) / 256)
#define NB_SCAN ((NN + 255) / 256)

typedef __attribute__((ext_vector_type(8))) short short8;
typedef __attribute__((ext_vector_type(4))) float floatx4;

// ---------------- bf16 helpers ----------------
__device__ __forceinline__ unsigned short f2bf(float f)
{
    union { float f; unsigned int u; } x; x.f = f;
    unsigned int r = x.u + 0x7fffu + ((x.u >> 16) & 1u);   // RNE
    return (unsigned short)(r >> 16);
}
__device__ __forceinline__ float bf2f(unsigned short u)
{
    union { unsigned int u; float f; } x; x.u = ((unsigned int)u) << 16;
    return x.f;
}

// ---------------- detect int32 vs int64 edge_index layout ----------------
__global__ void detect_kernel(const int* __restrict__ ei32, int* __restrict__ flag)
{
    if (threadIdx.x == 0 && blockIdx.x == 0) {
        int is64 = 1;
        for (int k = 0; k < 32; k++) {
            if (ei32[2 * k + 1] != 0) { is64 = 0; break; }
        }
        *flag = is64;
    }
}

__device__ __forceinline__ int load_idx(const int* ei32, int is64, int pos)
{
    return is64 ? ei32[2 * pos] : ei32[pos];
}

// ---------------- w_att precompute: w_att[h][f] = sum_c att[h][c] * W[h*128+c][f] ----------------
__global__ __launch_bounds__(256) void watt_kernel(const float* __restrict__ W,
                                                   const float* __restrict__ att_s,
                                                   const float* __restrict__ att_d,
                                                   float* __restrict__ ws,
                                                   float* __restrict__ wd)
{
    int hd = blockIdx.x;          // 0..1
    int f = threadIdx.x;          // 0..255
    float as = 0.f, ad = 0.f;
    for (int c = 0; c < CCOUT; c++) {
        float wv = W[(size_t)(hd * CCOUT + c) * FIN + f];
        as += att_s[hd * CCOUT + c] * wv;
        ad += att_d[hd * CCOUT + c] * wv;
    }
    ws[hd * FIN + f] = as;
    wd[hd * FIN + f] = ad;
}

// ---------------- fused x->bf16 conversion + exact fp32 attention logits ----------------
// one wave per node; lane l covers features l*4..l*4+3
__global__ __launch_bounds__(256) void xprep_kernel(const float* __restrict__ x,
                                                    const float* __restrict__ was,
                                                    const float* __restrict__ wad,
                                                    unsigned short* __restrict__ xb,
                                                    float* __restrict__ a_s,
                                                    float* __restrict__ a_d)
{
    int t = threadIdx.x;
    int w = t >> 6, l = t & 63;
    int n = blockIdx.x * 4 + w;
    float4 xv = *(const float4*)(x + (size_t)n * FIN + l * 4);
    ushort4 xs;
    xs.x = f2bf(xv.x); xs.y = f2bf(xv.y); xs.z = f2bf(xv.z); xs.w = f2bf(xv.w);
    *(ushort4*)(xb + (size_t)n * FIN + l * 4) = xs;

    float4 s0 = *(const float4*)(was + l * 4);
    float4 s1 = *(const float4*)(was + FIN + l * 4);
    float4 d0 = *(const float4*)(wad + l * 4);
    float4 d1 = *(const float4*)(wad + FIN + l * 4);
    float vs0 = xv.x * s0.x + xv.y * s0.y + xv.z * s0.z + xv.w * s0.w;
    float vs1 = xv.x * s1.x + xv.y * s1.y + xv.z * s1.z + xv.w * s1.w;
    float vd0 = xv.x * d0.x + xv.y * d0.y + xv.z * d0.z + xv.w * d0.w;
    float vd1 = xv.x * d1.x + xv.y * d1.y + xv.z * d1.z + xv.w * d1.w;
#pragma unroll
    for (int off = 32; off > 0; off >>= 1) {
        vs0 += __shfl_down(vs0, off);
        vs1 += __shfl_down(vs1, off);
        vd0 += __shfl_down(vd0, off);
        vd1 += __shfl_down(vd1, off);
    }
    if (l == 0) {
        a_s[n * 2 + 0] = vs0; a_s[n * 2 + 1] = vs1;
        a_d[n * 2 + 0] = vd0; a_d[n * 2 + 1] = vd1;
    }
}

// ---------------- fp32 -> bf16 weight conversion ----------------
__global__ __launch_bounds__(256) void convw_kernel(const float* __restrict__ src,
                                                    unsigned short* __restrict__ dst, int n4)
{
    int i = blockIdx.x * 256 + threadIdx.x;
    if (i >= n4) return;
    float4 v = *(const float4*)(src + (size_t)i * 4);
    ushort4 o;
    o.x = f2bf(v.x); o.y = f2bf(v.y); o.z = f2bf(v.z); o.w = f2bf(v.w);
    *(ushort4*)(dst + (size_t)i * 4) = o;
}

// ---------------- MFMA bf16 GEMM: C[M,N] = A[M,K] @ B[N,K]^T (+bias) ----------------
// 128x128 tile, BK=32, 4 waves (2x2 of 64x64), 16x16x32 MFMA
template <bool ADD_BIAS, bool OUT_BF16>
__global__ __launch_bounds__(256) void gemm_mfma(const unsigned short* __restrict__ A,
                                                 const unsigned short* __restrict__ B,
                                                 const float* __restrict__ bias,
                                                 void* __restrict__ Cout,
                                                 int M, int N, int K)
{
    const int LDT = 40;  // padded LDS row stride in shorts (32+8 -> conflict-free)
    __shared__ unsigned short As[128 * LDT];
    __shared__ unsigned short Bs[128 * LDT];

    int tid = threadIdx.x;
    int wave = tid >> 6, lane = tid & 63;
    int wr = wave >> 1, wc = wave & 1;
    int quad = lane >> 4, l16 = lane & 15;
    int bm0 = blockIdx.x * 128;
    int bn0 = blockIdx.y * 128;

    floatx4 acc[4][4] = {};

    for (int kk = 0; kk < K; kk += 32) {
#pragma unroll
        for (int p = 0; p < 2; p++) {
            int idx = p * 256 + tid;
            int row = idx >> 2, seg = idx & 3;
            int grow = bm0 + row; if (grow >= M) grow = M - 1;
            uint4 va = *(const uint4*)(A + (size_t)grow * K + kk + seg * 8);
            *(uint4*)(&As[row * LDT + seg * 8]) = va;
            uint4 vb = *(const uint4*)(B + (size_t)(bn0 + row) * K + kk + seg * 8);
            *(uint4*)(&Bs[row * LDT + seg * 8]) = vb;
        }
        __syncthreads();

        short8 af[4], bfr[4];
#pragma unroll
        for (int mi = 0; mi < 4; mi++)
            af[mi] = *(const short8*)(&As[(wr * 64 + mi * 16 + l16) * LDT + quad * 8]);
#pragma unroll
        for (int ni = 0; ni < 4; ni++)
            bfr[ni] = *(const short8*)(&Bs[(wc * 64 + ni * 16 + l16) * LDT + quad * 8]);
#pragma unroll
        for (int mi = 0; mi < 4; mi++)
#pragma unroll
            for (int ni = 0; ni < 4; ni++)
                acc[mi][ni] = __builtin_amdgcn_mfma_f32_16x16x32_bf16(af[mi], bfr[ni], acc[mi][ni], 0, 0, 0);
        __syncthreads();
    }

#pragma unroll
    for (int mi = 0; mi < 4; mi++) {
#pragma unroll
        for (int ni = 0; ni < 4; ni++) {
            int col = bn0 + wc * 64 + ni * 16 + l16;
#pragma unroll
            for (int r = 0; r < 4; r++) {
                int row = bm0 + wr * 64 + mi * 16 + quad * 4 + r;
                if (row < M) {
                    float v = acc[mi][ni][r];
                    if (ADD_BIAS) v += bias[col];
                    if (OUT_BF16)
                        ((unsigned short*)Cout)[(size_t)row * N + col] = f2bf(v);
                    else
                        ((float*)Cout)[(size_t)row * N + col] = v;
                }
            }
        }
    }
}

// ---------------- degree count ----------------
__global__ void count_kernel(const int* __restrict__ ei32, const int* __restrict__ flag,
                             int* __restrict__ deg)
{
    int e = blockIdx.x * blockDim.x + threadIdx.x;
    if (e >= ET) return;
    int is64 = *flag;
    int d = (e < EE) ? load_idx(ei32, is64, EE + e) : (e - EE);
    atomicAdd(&deg[d], 1);
}

// ---------------- 3-kernel exclusive scan over deg[NN] ----------------
__global__ __launch_bounds__(256) void scan1(const int* __restrict__ deg,
                                             int* __restrict__ tmp, int* __restrict__ bsum)
{
    __shared__ int s[256];
    int i = blockIdx.x * 256 + threadIdx.x;
    int v = (i < NN) ? deg[i] : 0;
    s[threadIdx.x] = v;
    __syncthreads();
    for (int off = 1; off < 256; off <<= 1) {
        int add = (threadIdx.x >= off) ? s[threadIdx.x - off] : 0;
        __syncthreads();
        s[threadIdx.x] += add;
        __syncthreads();
    }
    if (i < NN) tmp[i] = s[threadIdx.x];
    if (threadIdx.x == 255) bsum[blockIdx.x] = s[255];
}

__global__ __launch_bounds__(256) void scan2(int* __restrict__ bsum)
{
    __shared__ int s[256];
    int t = threadIdx.x;
    int v = (t < NB_SCAN) ? bsum[t] : 0;
    s[t] = v;
    __syncthreads();
    for (int off = 1; off < 256; off <<= 1) {
        int add = (t >= off) ? s[t - off] : 0;
        __syncthreads();
        s[t] += add;
        __syncthreads();
    }
    if (t < NB_SCAN) bsum[t] = s[t] - v;  // exclusive block offsets
}

__global__ __launch_bounds__(256) void scan3(const int* __restrict__ deg,
                                             const int* __restrict__ tmp,
                                             const int* __restrict__ bsum,
                                             int* __restrict__ rowstart)
{
    int i = blockIdx.x * 256 + threadIdx.x;
    if (i < NN) rowstart[i] = tmp[i] - deg[i] + bsum[blockIdx.x];
    if (i == 0) rowstart[NN] = ET;
}

// ---------------- scatter edges into CSR + denom ----------------
__global__ void scatter_kernel(const int* __restrict__ ei32, const int* __restrict__ flag,
                               const float* __restrict__ a_s, const float* __restrict__ a_d,
                               const int* __restrict__ rowstart, int* __restrict__ cursor,
                               int* __restrict__ csr_src, float* __restrict__ csr_p,
                               float* __restrict__ denom)
{
    int e = blockIdx.x * blockDim.x + threadIdx.x;
    if (e >= ET) return;
    int is64 = *flag;
    int s, d;
    if (e < EE) { s = load_idx(ei32, is64, e); d = load_idx(ei32, is64, EE + e); }
    else { s = d = e - EE; }
    float e0 = a_s[s * 2 + 0] + a_d[d * 2 + 0];
    float e1 = a_s[s * 2 + 1] + a_d[d * 2 + 1];
    e0 = e0 > 0.f ? e0 : NEG * e0;
    e1 = e1 > 0.f ? e1 : NEG * e1;
    float p0 = expf(e0);
    float p1 = expf(e1);
    int j = rowstart[d] + atomicAdd(&cursor[d], 1);
    csr_src[j] = s;
    csr_p[2 * j + 0] = p0;
    csr_p[2 * j + 1] = p1;
    atomicAdd(&denom[d * 2 + 0], p0);
    atomicAdd(&denom[d * 2 + 1], p1);
}

// ---------------- gather-aggregate (bf16 h) + bias + elu -> bf16 agg ----------------
// 2 nodes per block; 128 threads per node; each thread handles 2 channels (bf16x2)
__global__ __launch_bounds__(256) void agg2_kernel(const unsigned short* __restrict__ hb,
                                                   const int* __restrict__ rowstart,
                                                   const int* __restrict__ csr_src,
                                                   const float* __restrict__ csr_p,
                                                   const float* __restrict__ denom,
                                                   const float* __restrict__ bias,
                                                   unsigned short* __restrict__ aggb)
{
    int t = threadIdx.x;
    int d = blockIdx.x * 2 + (t >> 7);
    int tt = t & 127;
    int head = tt >> 6;
    int c = tt * 2;
    int j0 = rowstart[d], j1 = rowstart[d + 1];
    float acc0 = 0.f, acc1 = 0.f;
    int j = j0;
    for (; j + 1 < j1; j += 2) {
        int s0 = csr_src[j], s1 = csr_src[j + 1];
        float p0 = csr_p[2 * j + head];
        float p1 = csr_p[2 * (j + 1) + head];
        unsigned int v0 = *(const unsigned int*)(hb + (size_t)s0 * HC + c);
        unsigned int v1 = *(const unsigned int*)(hb + (size_t)s1 * HC + c);
        acc0 += p0 * bf2f((unsigned short)v0);
        acc1 += p0 * bf2f((unsigned short)(v0 >> 16));
        acc0 += p1 * bf2f((unsigned short)v1);
        acc1 += p1 * bf2f((unsigned short)(v1 >> 16));
    }
    if (j < j1) {
        int s0 = csr_src[j];
        float p0 = csr_p[2 * j + head];
        unsigned int v0 = *(const unsigned int*)(hb + (size_t)s0 * HC + c);
        acc0 += p0 * bf2f((unsigned short)v0);
        acc1 += p0 * bf2f((unsigned short)(v0 >> 16));
    }
    float den = fmaxf(denom[d * 2 + head], 1e-16f);
    float v0 = acc0 / den + bias[c];
    float v1 = acc1 / den + bias[c + 1];
    v0 = v0 > 0.f ? v0 : expm1f(v0);
    v1 = v1 > 0.f ? v1 : expm1f(v1);
    ushort2 o; o.x = f2bf(v0); o.y = f2bf(v1);
    *(ushort2*)(aggb + (size_t)d * HC + c) = o;
}

// ---------------- launch ----------------
extern "C" void kernel_launch(void* const* d_in, const int* in_sizes, int n_in,
                              void* d_out, int out_size, void* d_ws, size_t ws_size,
                              hipStream_t stream)
{
    const float* x       = (const float*)d_in[0];
    const int*   ei32    = (const int*)d_in[1];
    const float* W       = (const float*)d_in[2];
    const float* att_src = (const float*)d_in[3];
    const float* att_dst = (const float*)d_in[4];
    const float* bias    = (const float*)d_in[5];
    const float* lin_w   = (const float*)d_in[6];
    const float* lin_b   = (const float*)d_in[7];
    float* out = (float*)d_out;

    char* ws = (char*)d_ws;
    size_t off = 0;
    auto alloc = [&](size_t bytes) -> void* {
        void* p = ws + off;
        off += (bytes + 255) & ~(size_t)255;
        return p;
    };

    // zero-init region first (deg, cursor, denom)
    int*   deg    = (int*)alloc((size_t)NN * 4);
    int*   cursor = (int*)alloc((size_t)NN * 4);
    float* denom  = (float*)alloc((size_t)NN * 2 * 4);
    size_t zero_bytes = off;

    int*   flag     = (int*)alloc(256);
    int*   tmp      = (int*)alloc((size_t)NN * 4);
    int*   bsum     = (int*)alloc(1024);
    int*   rowstart = (int*)alloc((size_t)(NN + 1) * 4);
    float* was      = (float*)alloc((size_t)HH * FIN * 4);
    float* wad      = (float*)alloc((size_t)HH * FIN * 4);
    float* a_s      = (float*)alloc((size_t)NN * 2 * 4);
    float* a_d      = (float*)alloc((size_t)NN * 2 * 4);
    int*   csr_src  = (int*)alloc((size_t)ET * 4);
    float* csr_p    = (float*)alloc((size_t)ET * 2 * 4);
    unsigned short* xb     = (unsigned short*)alloc((size_t)NN * FIN * 2);
    unsigned short* Wb     = (unsigned short*)alloc((size_t)HC * FIN * 2);
    unsigned short* linwb  = (unsigned short*)alloc((size_t)CCOUT * HC * 2);
    unsigned short* hb     = (unsigned short*)alloc((size_t)NN * HC * 2);
    unsigned short* aggb   = (unsigned short*)alloc((size_t)NN * HC * 2);

    hipMemsetAsync(d_ws, 0, zero_bytes, stream);

    detect_kernel<<<1, 64, 0, stream>>>(ei32, flag);

    watt_kernel<<<HH, 256, 0, stream>>>(W, att_src, att_dst, was, wad);

    xprep_kernel<<<NN / 4, 256, 0, stream>>>(x, was, wad, xb, a_s, a_d);

    convw_kernel<<<(HC * FIN / 4 + 255) / 256, 256, 0, stream>>>(W, Wb, HC * FIN / 4);
    convw_kernel<<<(CCOUT * HC / 4 + 255) / 256, 256, 0, stream>>>(lin_w, linwb, CCOUT * HC / 4);

    count_kernel<<<NB_EDGE, 256, 0, stream>>>(ei32, flag, deg);

    scan1<<<NB_SCAN, 256, 0, stream>>>(deg, tmp, bsum);
    scan2<<<1, 256, 0, stream>>>(bsum);
    scan3<<<NB_SCAN, 256, 0, stream>>>(deg, tmp, bsum, rowstart);

    scatter_kernel<<<NB_EDGE, 256, 0, stream>>>(ei32, flag, a_s, a_d, rowstart,
                                                cursor, csr_src, csr_p, denom);

    dim3 g1((NN + 127) / 128, HC / 128);
    gemm_mfma<false, true><<<g1, 256, 0, stream>>>(xb, Wb, nullptr, hb, NN, HC, FIN);

    agg2_kernel<<<NN / 2, 256, 0, stream>>>(hb, rowstart, csr_src, csr_p, denom, bias, aggb);

    dim3 g2((NN + 127) / 128, CCOUT / 128);
    gemm_mfma<true, false><<<g2, 256, 0, stream>>>(aggb, linwb, lin_b, out, NN, CCOUT, HC);
}

// Round 3
// 284.774 us; speedup vs baseline: 2.2512x; 1.5062x over previous
//
#include <hip/hip_runtime.h>
#include <math.h>

#define NN 50000
#define EE 800000
#define ET (EE + NN)
#define FIN 256
#define CCOUT 128
#define HH 2
#define HC 256
#define NEG 0.2f

#define NB_EDGE ((ET + 255) / 256)
#define NB_SCAN ((NN + 255) / 256)

typedef __attribute__((ext_vector_type(8))) short short8;
typedef __attribute__((ext_vector_type(4))) float floatx4;

// ---------------- bf16 helpers ----------------
__device__ __forceinline__ unsigned short f2bf(float f)
{
    union { float f; unsigned int u; } x; x.f = f;
    unsigned int r = x.u + 0x7fffu + ((x.u >> 16) & 1u);   // RNE
    return (unsigned short)(r >> 16);
}
__device__ __forceinline__ float bf2f(unsigned short u)
{
    union { unsigned int u; float f; } x; x.u = ((unsigned int)u) << 16;
    return x.f;
}

// ---------------- detect int32 vs int64 edge_index layout ----------------
__global__ void detect_kernel(const int* __restrict__ ei32, int* __restrict__ flag)
{
    if (threadIdx.x == 0 && blockIdx.x == 0) {
        int is64 = 1;
        for (int k = 0; k < 32; k++) {
            if (ei32[2 * k + 1] != 0) { is64 = 0; break; }
        }
        *flag = is64;
    }
}

__device__ __forceinline__ int load_idx(const int* ei32, int is64, int pos)
{
    return is64 ? ei32[2 * pos] : ei32[pos];
}

// ---------------- w_att precompute: w_att[h][f] = sum_c att[h][c] * W[h*128+c][f] ----------------
__global__ __launch_bounds__(256) void watt_kernel(const float* __restrict__ W,
                                                   const float* __restrict__ att_s,
                                                   const float* __restrict__ att_d,
                                                   float* __restrict__ ws,
                                                   float* __restrict__ wd)
{
    int hd = blockIdx.x;          // 0..1
    int f = threadIdx.x;          // 0..255
    float as = 0.f, ad = 0.f;
    for (int c = 0; c < CCOUT; c++) {
        float wv = W[(size_t)(hd * CCOUT + c) * FIN + f];
        as += att_s[hd * CCOUT + c] * wv;
        ad += att_d[hd * CCOUT + c] * wv;
    }
    ws[hd * FIN + f] = as;
    wd[hd * FIN + f] = ad;
}

// ---------------- fused x->bf16 conversion + exact fp32 attention logits ----------------
__global__ __launch_bounds__(256) void xprep_kernel(const float* __restrict__ x,
                                                    const float* __restrict__ was,
                                                    const float* __restrict__ wad,
                                                    unsigned short* __restrict__ xb,
                                                    float* __restrict__ a_s,
                                                    float* __restrict__ a_d)
{
    int t = threadIdx.x;
    int w = t >> 6, l = t & 63;
    int n = blockIdx.x * 4 + w;
    float4 xv = *(const float4*)(x + (size_t)n * FIN + l * 4);
    ushort4 xs;
    xs.x = f2bf(xv.x); xs.y = f2bf(xv.y); xs.z = f2bf(xv.z); xs.w = f2bf(xv.w);
    *(ushort4*)(xb + (size_t)n * FIN + l * 4) = xs;

    float4 s0 = *(const float4*)(was + l * 4);
    float4 s1 = *(const float4*)(was + FIN + l * 4);
    float4 d0 = *(const float4*)(wad + l * 4);
    float4 d1 = *(const float4*)(wad + FIN + l * 4);
    float vs0 = xv.x * s0.x + xv.y * s0.y + xv.z * s0.z + xv.w * s0.w;
    float vs1 = xv.x * s1.x + xv.y * s1.y + xv.z * s1.z + xv.w * s1.w;
    float vd0 = xv.x * d0.x + xv.y * d0.y + xv.z * d0.z + xv.w * d0.w;
    float vd1 = xv.x * d1.x + xv.y * d1.y + xv.z * d1.z + xv.w * d1.w;
#pragma unroll
    for (int off = 32; off > 0; off >>= 1) {
        vs0 += __shfl_down(vs0, off);
        vs1 += __shfl_down(vs1, off);
        vd0 += __shfl_down(vd0, off);
        vd1 += __shfl_down(vd1, off);
    }
    if (l == 0) {
        a_s[n * 2 + 0] = vs0; a_s[n * 2 + 1] = vs1;
        a_d[n * 2 + 0] = vd0; a_d[n * 2 + 1] = vd1;
    }
}

// ---------------- fp32 -> bf16 weight conversion ----------------
__global__ __launch_bounds__(256) void convw_kernel(const float* __restrict__ src,
                                                    unsigned short* __restrict__ dst, int n4)
{
    int i = blockIdx.x * 256 + threadIdx.x;
    if (i >= n4) return;
    float4 v = *(const float4*)(src + (size_t)i * 4);
    ushort4 o;
    o.x = f2bf(v.x); o.y = f2bf(v.y); o.z = f2bf(v.z); o.w = f2bf(v.w);
    *(ushort4*)(dst + (size_t)i * 4) = o;
}

// ---------------- MFMA bf16 GEMM: C[M,N] = A[M,K] @ B[N,K]^T (+bias) ----------------
template <bool ADD_BIAS, bool OUT_BF16>
__global__ __launch_bounds__(256) void gemm_mfma(const unsigned short* __restrict__ A,
                                                 const unsigned short* __restrict__ B,
                                                 const float* __restrict__ bias,
                                                 void* __restrict__ Cout,
                                                 int M, int N, int K)
{
    const int LDT = 40;
    __shared__ unsigned short As[128 * LDT];
    __shared__ unsigned short Bs[128 * LDT];

    int tid = threadIdx.x;
    int wave = tid >> 6, lane = tid & 63;
    int wr = wave >> 1, wc = wave & 1;
    int quad = lane >> 4, l16 = lane & 15;
    int bm0 = blockIdx.x * 128;
    int bn0 = blockIdx.y * 128;

    floatx4 acc[4][4] = {};

    for (int kk = 0; kk < K; kk += 32) {
#pragma unroll
        for (int p = 0; p < 2; p++) {
            int idx = p * 256 + tid;
            int row = idx >> 2, seg = idx & 3;
            int grow = bm0 + row; if (grow >= M) grow = M - 1;
            uint4 va = *(const uint4*)(A + (size_t)grow * K + kk + seg * 8);
            *(uint4*)(&As[row * LDT + seg * 8]) = va;
            uint4 vb = *(const uint4*)(B + (size_t)(bn0 + row) * K + kk + seg * 8);
            *(uint4*)(&Bs[row * LDT + seg * 8]) = vb;
        }
        __syncthreads();

        short8 af[4], bfr[4];
#pragma unroll
        for (int mi = 0; mi < 4; mi++)
            af[mi] = *(const short8*)(&As[(wr * 64 + mi * 16 + l16) * LDT + quad * 8]);
#pragma unroll
        for (int ni = 0; ni < 4; ni++)
            bfr[ni] = *(const short8*)(&Bs[(wc * 64 + ni * 16 + l16) * LDT + quad * 8]);
#pragma unroll
        for (int mi = 0; mi < 4; mi++)
#pragma unroll
            for (int ni = 0; ni < 4; ni++)
                acc[mi][ni] = __builtin_amdgcn_mfma_f32_16x16x32_bf16(af[mi], bfr[ni], acc[mi][ni], 0, 0, 0);
        __syncthreads();
    }

#pragma unroll
    for (int mi = 0; mi < 4; mi++) {
#pragma unroll
        for (int ni = 0; ni < 4; ni++) {
            int col = bn0 + wc * 64 + ni * 16 + l16;
#pragma unroll
            for (int r = 0; r < 4; r++) {
                int row = bm0 + wr * 64 + mi * 16 + quad * 4 + r;
                if (row < M) {
                    float v = acc[mi][ni][r];
                    if (ADD_BIAS) v += bias[col];
                    if (OUT_BF16)
                        ((unsigned short*)Cout)[(size_t)row * N + col] = f2bf(v);
                    else
                        ((float*)Cout)[(size_t)row * N + col] = v;
                }
            }
        }
    }
}

// ---------------- degree count + per-edge local offset ----------------
__global__ void count_kernel(const int* __restrict__ ei32, const int* __restrict__ flag,
                             int* __restrict__ deg, int* __restrict__ eord)
{
    int e = blockIdx.x * blockDim.x + threadIdx.x;
    if (e >= ET) return;
    int is64 = *flag;
    int d = (e < EE) ? load_idx(ei32, is64, EE + e) : (e - EE);
    eord[e] = atomicAdd(&deg[d], 1);
}

// ---------------- 3-kernel exclusive scan over deg[NN] ----------------
__global__ __launch_bounds__(256) void scan1(const int* __restrict__ deg,
                                             int* __restrict__ tmp, int* __restrict__ bsum)
{
    __shared__ int s[256];
    int i = blockIdx.x * 256 + threadIdx.x;
    int v = (i < NN) ? deg[i] : 0;
    s[threadIdx.x] = v;
    __syncthreads();
    for (int off = 1; off < 256; off <<= 1) {
        int add = (threadIdx.x >= off) ? s[threadIdx.x - off] : 0;
        __syncthreads();
        s[threadIdx.x] += add;
        __syncthreads();
    }
    if (i < NN) tmp[i] = s[threadIdx.x];
    if (threadIdx.x == 255) bsum[blockIdx.x] = s[255];
}

__global__ __launch_bounds__(256) void scan2(int* __restrict__ bsum)
{
    __shared__ int s[256];
    int t = threadIdx.x;
    int v = (t < NB_SCAN) ? bsum[t] : 0;
    s[t] = v;
    __syncthreads();
    for (int off = 1; off < 256; off <<= 1) {
        int add = (t >= off) ? s[t - off] : 0;
        __syncthreads();
        s[t] += add;
        __syncthreads();
    }
    if (t < NB_SCAN) bsum[t] = s[t] - v;  // exclusive block offsets
}

__global__ __launch_bounds__(256) void scan3(const int* __restrict__ deg,
                                             const int* __restrict__ tmp,
                                             const int* __restrict__ bsum,
                                             int* __restrict__ rowstart)
{
    int i = blockIdx.x * 256 + threadIdx.x;
    if (i < NN) rowstart[i] = tmp[i] - deg[i] + bsum[blockIdx.x];
    if (i == 0) rowstart[NN] = ET;
}

// ---------------- CSR build: atomic-free, 4 B/edge scattered write ----------------
__global__ void scatter_kernel(const int* __restrict__ ei32, const int* __restrict__ flag,
                               const int* __restrict__ eord,
                               const int* __restrict__ rowstart,
                               int* __restrict__ csr_src)
{
    int e = blockIdx.x * blockDim.x + threadIdx.x;
    if (e >= ET) return;
    int is64 = *flag;
    int s, d;
    if (e < EE) { s = load_idx(ei32, is64, e); d = load_idx(ei32, is64, EE + e); }
    else { s = d = e - EE; }
    csr_src[rowstart[d] + eord[e]] = s;
}

// ---------------- gather-aggregate, wave-per-node, p + denom recomputed inline ----------------
// 4 waves/block = 4 nodes/block. Lane: head = lane>>5, 4 channels = (lane&31)*4 + head*128.
__global__ __launch_bounds__(256) void agg3_kernel(const unsigned short* __restrict__ hb,
                                                   const int* __restrict__ rowstart,
                                                   const int* __restrict__ csr_src,
                                                   const float* __restrict__ a_s,
                                                   const float* __restrict__ a_d,
                                                   const float* __restrict__ bias,
                                                   unsigned short* __restrict__ aggb)
{
    int wave = threadIdx.x >> 6, lane = threadIdx.x & 63;
    int d = blockIdx.x * 4 + wave;
    int head = lane >> 5;
    int c = (lane & 31) * 4 + head * 128;
    float a_dv = a_d[d * 2 + head];
    int j0 = rowstart[d], j1 = rowstart[d + 1];

    float acc0 = 0.f, acc1 = 0.f, acc2 = 0.f, acc3 = 0.f, psum = 0.f;

    int j = j0;
    for (; j + 3 < j1; j += 4) {
        int s0 = csr_src[j], s1 = csr_src[j + 1], s2 = csr_src[j + 2], s3 = csr_src[j + 3];
        float e0 = a_s[s0 * 2 + head] + a_dv;
        float e1 = a_s[s1 * 2 + head] + a_dv;
        float e2 = a_s[s2 * 2 + head] + a_dv;
        float e3 = a_s[s3 * 2 + head] + a_dv;
        e0 = e0 > 0.f ? e0 : NEG * e0;
        e1 = e1 > 0.f ? e1 : NEG * e1;
        e2 = e2 > 0.f ? e2 : NEG * e2;
        e3 = e3 > 0.f ? e3 : NEG * e3;
        float p0 = __expf(e0), p1 = __expf(e1), p2 = __expf(e2), p3 = __expf(e3);
        psum += p0 + p1 + p2 + p3;
        uint2 h0 = *(const uint2*)(hb + (size_t)s0 * HC + c);
        uint2 h1 = *(const uint2*)(hb + (size_t)s1 * HC + c);
        uint2 h2 = *(const uint2*)(hb + (size_t)s2 * HC + c);
        uint2 h3 = *(const uint2*)(hb + (size_t)s3 * HC + c);
        acc0 += p0 * bf2f((unsigned short)h0.x) + p1 * bf2f((unsigned short)h1.x)
              + p2 * bf2f((unsigned short)h2.x) + p3 * bf2f((unsigned short)h3.x);
        acc1 += p0 * bf2f((unsigned short)(h0.x >> 16)) + p1 * bf2f((unsigned short)(h1.x >> 16))
              + p2 * bf2f((unsigned short)(h2.x >> 16)) + p3 * bf2f((unsigned short)(h3.x >> 16));
        acc2 += p0 * bf2f((unsigned short)h0.y) + p1 * bf2f((unsigned short)h1.y)
              + p2 * bf2f((unsigned short)h2.y) + p3 * bf2f((unsigned short)h3.y);
        acc3 += p0 * bf2f((unsigned short)(h0.y >> 16)) + p1 * bf2f((unsigned short)(h1.y >> 16))
              + p2 * bf2f((unsigned short)(h2.y >> 16)) + p3 * bf2f((unsigned short)(h3.y >> 16));
    }
    for (; j < j1; j++) {
        int s0 = csr_src[j];
        float e0 = a_s[s0 * 2 + head] + a_dv;
        e0 = e0 > 0.f ? e0 : NEG * e0;
        float p0 = __expf(e0);
        psum += p0;
        uint2 h0 = *(const uint2*)(hb + (size_t)s0 * HC + c);
        acc0 += p0 * bf2f((unsigned short)h0.x);
        acc1 += p0 * bf2f((unsigned short)(h0.x >> 16));
        acc2 += p0 * bf2f((unsigned short)h0.y);
        acc3 += p0 * bf2f((unsigned short)(h0.y >> 16));
    }

    float inv = 1.f / fmaxf(psum, 1e-16f);
    float v0 = acc0 * inv + bias[c + 0];
    float v1 = acc1 * inv + bias[c + 1];
    float v2 = acc2 * inv + bias[c + 2];
    float v3 = acc3 * inv + bias[c + 3];
    v0 = v0 > 0.f ? v0 : expm1f(v0);
    v1 = v1 > 0.f ? v1 : expm1f(v1);
    v2 = v2 > 0.f ? v2 : expm1f(v2);
    v3 = v3 > 0.f ? v3 : expm1f(v3);
    ushort4 o;
    o.x = f2bf(v0); o.y = f2bf(v1); o.z = f2bf(v2); o.w = f2bf(v3);
    *(ushort4*)(aggb + (size_t)d * HC + c) = o;
}

// ---------------- launch ----------------
extern "C" void kernel_launch(void* const* d_in, const int* in_sizes, int n_in,
                              void* d_out, int out_size, void* d_ws, size_t ws_size,
                              hipStream_t stream)
{
    const float* x       = (const float*)d_in[0];
    const int*   ei32    = (const int*)d_in[1];
    const float* W       = (const float*)d_in[2];
    const float* att_src = (const float*)d_in[3];
    const float* att_dst = (const float*)d_in[4];
    const float* bias    = (const float*)d_in[5];
    const float* lin_w   = (const float*)d_in[6];
    const float* lin_b   = (const float*)d_in[7];
    float* out = (float*)d_out;

    char* ws = (char*)d_ws;
    size_t off = 0;
    auto alloc = [&](size_t bytes) -> void* {
        void* p = ws + off;
        off += (bytes + 255) & ~(size_t)255;
        return p;
    };

    // zero-init region first (deg only)
    int*   deg    = (int*)alloc((size_t)NN * 4);
    size_t zero_bytes = off;

    int*   flag     = (int*)alloc(256);
    int*   tmp      = (int*)alloc((size_t)NN * 4);
    int*   bsum     = (int*)alloc(1024);
    int*   rowstart = (int*)alloc((size_t)(NN + 1) * 4);
    int*   eord     = (int*)alloc((size_t)ET * 4);
    float* was      = (float*)alloc((size_t)HH * FIN * 4);
    float* wad      = (float*)alloc((size_t)HH * FIN * 4);
    float* a_s      = (float*)alloc((size_t)NN * 2 * 4);
    float* a_d      = (float*)alloc((size_t)NN * 2 * 4);
    int*   csr_src  = (int*)alloc((size_t)ET * 4);
    unsigned short* xb     = (unsigned short*)alloc((size_t)NN * FIN * 2);
    unsigned short* Wb     = (unsigned short*)alloc((size_t)HC * FIN * 2);
    unsigned short* linwb  = (unsigned short*)alloc((size_t)CCOUT * HC * 2);
    unsigned short* hb     = (unsigned short*)alloc((size_t)NN * HC * 2);
    unsigned short* aggb   = (unsigned short*)alloc((size_t)NN * HC * 2);

    hipMemsetAsync(d_ws, 0, zero_bytes, stream);

    detect_kernel<<<1, 64, 0, stream>>>(ei32, flag);

    count_kernel<<<NB_EDGE, 256, 0, stream>>>(ei32, flag, deg, eord);

    watt_kernel<<<HH, 256, 0, stream>>>(W, att_src, att_dst, was, wad);

    xprep_kernel<<<NN / 4, 256, 0, stream>>>(x, was, wad, xb, a_s, a_d);

    convw_kernel<<<(HC * FIN / 4 + 255) / 256, 256, 0, stream>>>(W, Wb, HC * FIN / 4);
    convw_kernel<<<(CCOUT * HC / 4 + 255) / 256, 256, 0, stream>>>(lin_w, linwb, CCOUT * HC / 4);

    scan1<<<NB_SCAN, 256, 0, stream>>>(deg, tmp, bsum);
    scan2<<<1, 256, 0, stream>>>(bsum);
    scan3<<<NB_SCAN, 256, 0, stream>>>(deg, tmp, bsum, rowstart);

    scatter_kernel<<<NB_EDGE, 256, 0, stream>>>(ei32, flag, eord, rowstart, csr_src);

    dim3 g1((NN + 127) / 128, HC / 128);
    gemm_mfma<false, true><<<g1, 256, 0, stream>>>(xb, Wb, nullptr, hb, NN, HC, FIN);

    agg3_kernel<<<NN / 4, 256, 0, stream>>>(hb, rowstart, csr_src, a_s, a_d, bias, aggb);

    dim3 g2((NN + 127) / 128, CCOUT / 128);
    gemm_mfma<true, false><<<g2, 256, 0, stream>>>(aggb, linwb, lin_b, out, NN, CCOUT, HC);
}